// Round 1
// baseline (832.776 us; speedup 1.0000x reference)
//
#include <hip/hip_runtime.h>

// GraphAttention: N=12288, IN=OUT=128.
// e_new = emb@W.T ; s = e_new@a1 ; t = e_new@a2
// e[i][j] = leaky(s_i + t_j) masked by adj; softmax rows; out = relu(att @ e_new)
//
//  k1: bf16 MFMA gemm emb@W.T -> Vt (bf16, transposed [d][j]); s,t stored
//      PRE-SCALED by log2(e) so k2 runs softmax in exp2 domain.
//  ktmax: TmaxK = max_j tK_j (exact row max bound since leaky is monotonic)
//  k2: streaming masked-softmax-PV.
//      - adj/t: direct global->reg (zero cross-thread reuse; LDS staging was
//        pure overhead), double-buffered in registers.
//      - Vt: global_load_lds DMA into 4-buffer LDS ring, 2 chunks ahead.
//        Per-lane SOURCE addresses carry an XOR swizzle (colgrp ^= (row>>1)&3)
//        so the linear DMA landing gives <=2-way (free) bank aliasing on the
//        ds_read_b128 fragment reads.
//      - raw s_barrier + counted s_waitcnt vmcnt(4): prefetches survive the
//        barrier (compiler's __syncthreads would drain vmcnt(0) every chunk).
//  k3: reduce col-split partials + denominators + normalize + relu (kl fused).

#define NN 12288
#define DIM 128
#define CSPLIT 8
#define COLS_PER (NN / CSPLIT)   // 1536
#define BK 32
#define NCHUNK (COLS_PER / BK)   // 48
#define LOG2E 1.4426950408889634f

typedef __bf16 bf16x8 __attribute__((ext_vector_type(8)));
typedef float f32x4 __attribute__((ext_vector_type(4)));

__device__ __forceinline__ void gl_lds16(const __bf16* g, __bf16* l) {
  __builtin_amdgcn_global_load_lds(
      (const __attribute__((address_space(1))) void*)g,
      (__attribute__((address_space(3))) void*)l, 16, 0, 0);
}

// ---------------- kernel 1: e_new = emb @ W.T (bf16 MFMA), emits Vt, sK, tK --
__global__ __launch_bounds__(256) void k1_gemm(const float* __restrict__ emb,
                                               const float* __restrict__ W,
                                               const float* __restrict__ a,
                                               __bf16* __restrict__ Vt,
                                               float* __restrict__ s,
                                               float* __restrict__ t) {
  const int lane = threadIdx.x & 63;
  const int wave = threadIdx.x >> 6;
  const int m = lane & 15;
  const int quad = lane >> 4;
  const int row0 = blockIdx.x * 64 + wave * 16;  // this wave: 16 rows

  f32x4 acc[8];
#pragma unroll
  for (int nb = 0; nb < 8; nb++) acc[nb] = (f32x4){0.f, 0.f, 0.f, 0.f};

#pragma unroll
  for (int ks = 0; ks < 4; ks++) {
    const int k0 = ks * 32 + quad * 8;
    const float* ep = emb + (size_t)(row0 + m) * DIM + k0;
    float4 lo = *(const float4*)ep;
    float4 hi = *(const float4*)(ep + 4);
    bf16x8 af = {(__bf16)lo.x, (__bf16)lo.y, (__bf16)lo.z, (__bf16)lo.w,
                 (__bf16)hi.x, (__bf16)hi.y, (__bf16)hi.z, (__bf16)hi.w};
#pragma unroll
    for (int nb = 0; nb < 8; nb++) {
      const float* wp = W + (size_t)(nb * 16 + m) * DIM + k0;
      float4 wlo = *(const float4*)wp;
      float4 whi = *(const float4*)(wp + 4);
      bf16x8 bf = {(__bf16)wlo.x, (__bf16)wlo.y, (__bf16)wlo.z, (__bf16)wlo.w,
                   (__bf16)whi.x, (__bf16)whi.y, (__bf16)whi.z, (__bf16)whi.w};
      acc[nb] = __builtin_amdgcn_mfma_f32_16x16x32_bf16(af, bf, acc[nb], 0, 0, 0);
    }
  }

  float a1v[8], a2v[8];
#pragma unroll
  for (int nb = 0; nb < 8; nb++) {
    a1v[nb] = a[nb * 16 + m];
    a2v[nb] = a[DIM + nb * 16 + m];
  }
  // C/D layout: row = quad*4 + r, col = nb*16 + m
#pragma unroll
  for (int r = 0; r < 4; r++) {
    const int gr = row0 + quad * 4 + r;
    float ps = 0.f, pt = 0.f;
#pragma unroll
    for (int nb = 0; nb < 8; nb++) {
      float e = acc[nb][r];
      ps += e * a1v[nb];
      pt += e * a2v[nb];
      Vt[(size_t)(nb * 16 + m) * NN + gr] = (__bf16)e;
    }
    ps += __shfl_xor(ps, 1); ps += __shfl_xor(ps, 2);
    ps += __shfl_xor(ps, 4); ps += __shfl_xor(ps, 8);
    pt += __shfl_xor(pt, 1); pt += __shfl_xor(pt, 2);
    pt += __shfl_xor(pt, 4); pt += __shfl_xor(pt, 8);
    if (m == 0) { s[gr] = ps * LOG2E; t[gr] = pt * LOG2E; }
  }
}

// ---------------- kernel: TmaxK = max(tK) -----------------------------------
__global__ __launch_bounds__(256) void ktmax(const float* __restrict__ t,
                                             float* __restrict__ tmax) {
  __shared__ float red[4];
  const float4* t4 = (const float4*)t;
  float mx = -3.0e38f;
#pragma unroll
  for (int i = 0; i < NN / 4 / 256; i++) {  // 12 iters, independent loads
    float4 v = t4[i * 256 + threadIdx.x];
    mx = fmaxf(mx, fmaxf(fmaxf(v.x, v.y), fmaxf(v.z, v.w)));
  }
#pragma unroll
  for (int off = 1; off < 64; off <<= 1) mx = fmaxf(mx, __shfl_xor(mx, off));
  if ((threadIdx.x & 63) == 0) red[threadIdx.x >> 6] = mx;
  __syncthreads();
  if (threadIdx.x == 0)
    *tmax = fmaxf(fmaxf(red[0], red[1]), fmaxf(red[2], red[3]));
}

// ---------------- kernel 2: masked softmax + PV ------------------------------
#define PELS(P, AA0, AA1, T0, T1, SS, MM, LL)                                   \
  {                                                                             \
    float v0 = SS + T0.x, v1 = SS + T0.y, v2 = SS + T0.z, v3 = SS + T0.w;       \
    float v4 = SS + T1.x, v5 = SS + T1.y, v6 = SS + T1.z, v7 = SS + T1.w;       \
    float e0 = (AA0.x != 0) ? __builtin_amdgcn_exp2f(fmaxf(v0, 0.01f * v0) - MM) : 0.f; \
    float e1 = (AA0.y != 0) ? __builtin_amdgcn_exp2f(fmaxf(v1, 0.01f * v1) - MM) : 0.f; \
    float e2 = (AA0.z != 0) ? __builtin_amdgcn_exp2f(fmaxf(v2, 0.01f * v2) - MM) : 0.f; \
    float e3 = (AA0.w != 0) ? __builtin_amdgcn_exp2f(fmaxf(v3, 0.01f * v3) - MM) : 0.f; \
    float e4 = (AA1.x != 0) ? __builtin_amdgcn_exp2f(fmaxf(v4, 0.01f * v4) - MM) : 0.f; \
    float e5 = (AA1.y != 0) ? __builtin_amdgcn_exp2f(fmaxf(v5, 0.01f * v5) - MM) : 0.f; \
    float e6 = (AA1.z != 0) ? __builtin_amdgcn_exp2f(fmaxf(v6, 0.01f * v6) - MM) : 0.f; \
    float e7 = (AA1.w != 0) ? __builtin_amdgcn_exp2f(fmaxf(v7, 0.01f * v7) - MM) : 0.f; \
    LL += ((e0 + e1) + (e2 + e3)) + ((e4 + e5) + (e6 + e7));                    \
    P[0] = (__bf16)e0; P[1] = (__bf16)e1; P[2] = (__bf16)e2; P[3] = (__bf16)e3; \
    P[4] = (__bf16)e4; P[5] = (__bf16)e5; P[6] = (__bf16)e6; P[7] = (__bf16)e7; \
  }

#define FETCH(cc, A0A, A1A, A0B, A1B, T0, T1)                                   \
  {                                                                             \
    const int off = (cc) * BK;                                                  \
    A0A = *(const int4*)(abase + off); A1A = *(const int4*)(abase + off + 4);   \
    A0B = *(const int4*)(bbase + off); A1B = *(const int4*)(bbase + off + 4);   \
    T0 = *(const float4*)(tbase + off); T1 = *(const float4*)(tbase + off + 4); \
  }

#define DMA2(cc)                                                                \
  {                                                                             \
    __bf16* d = &vtb[(cc) & 3][dst0];                                           \
    gl_lds16(vsrc0 + (size_t)(cc) * BK, d);                                     \
    gl_lds16(vsrc1 + (size_t)(cc) * BK, d + 512);                               \
  }

#define COMPUTE(cc, A0A, A1A, A0B, A1B, T0, T1)                                 \
  {                                                                             \
    const __bf16* vb = &vtb[(cc) & 3][vread];                                   \
    bf16x8 pA, pB;                                                              \
    PELS(pA, A0A, A1A, T0, T1, sA, mA, lA)                                      \
    PELS(pB, A0B, A1B, T0, T1, sB, mB, lB)                                      \
    _Pragma("unroll")                                                           \
    for (int nb = 0; nb < 8; nb++) {                                            \
      bf16x8 bv = *(const bf16x8*)(vb + nb * 512);                              \
      accA[nb] = __builtin_amdgcn_mfma_f32_16x16x32_bf16(pA, bv, accA[nb], 0, 0, 0); \
      accB[nb] = __builtin_amdgcn_mfma_f32_16x16x32_bf16(pB, bv, accB[nb], 0, 0, 0); \
    }                                                                           \
  }

__global__ __launch_bounds__(256, 3) void k2_attn(const int* __restrict__ adj,
                                                  const __bf16* __restrict__ Vt,
                                                  const float* __restrict__ sK,
                                                  const float* __restrict__ tK,
                                                  const float* __restrict__ tmaxp,
                                                  float* __restrict__ part,
                                                  float* __restrict__ lpart) {
  // 4-deep ring of Vt tiles: 128 dims x 32 cols bf16 = 8KB each, XOR-swizzled.
  __shared__ __attribute__((aligned(16))) __bf16 vtb[4][4096];

  const int tid = threadIdx.x;
  const int lane = tid & 63;
  const int wave = tid >> 6;
  const int m = lane & 15;
  const int quad = lane >> 4;
  const int row0 = blockIdx.x * 128;
  const int cs = blockIdx.y;
  const int col0 = cs * COLS_PER;
  const int rowA = row0 + wave * 32 + m;
  const int rowB = rowA + 16;

  const float TmaxK = *tmaxp;
  const float sA = sK[rowA], sB = sK[rowB];
  const float uA = sA + TmaxK, uB = sB + TmaxK;
  const float mA = fmaxf(uA, 0.01f * uA);  // exact row softmax shift (leaky monotonic)
  const float mB = fmaxf(uB, 0.01f * uB);

  // DMA source swizzle: LDS slot p (16B) = wave*128 + instr*64 + lane;
  // row = p>>2, cg' = p&3, source colgrp = cg' ^ ((row>>1)&3).
  const int p0 = wave * 128 + lane;
  const int r0d = p0 >> 2;
  const int cg0 = (p0 & 3) ^ ((r0d >> 1) & 3);  // (r0d+16)>>1 has same &3 -> shared
  const __bf16* vsrc0 = Vt + (size_t)r0d * NN + col0 + cg0 * 8;
  const __bf16* vsrc1 = vsrc0 + (size_t)16 * NN;
  const int dst0 = wave * 1024;
  // fragment read: row=nb*16+m, colgrp=quad -> slot row*4 + (quad^((m>>1)&3))
  const int vread = (m * 4 + (quad ^ ((m >> 1) & 3))) * 8;

  const int* abase = adj + (size_t)rowA * NN + col0 + quad * 8;
  const int* bbase = adj + (size_t)rowB * NN + col0 + quad * 8;
  const float* tbase = tK + col0 + quad * 8;

  f32x4 accA[8], accB[8];
#pragma unroll
  for (int nb = 0; nb < 8; nb++) {
    accA[nb] = (f32x4){0.f, 0.f, 0.f, 0.f};
    accB[nb] = (f32x4){0.f, 0.f, 0.f, 0.f};
  }
  float lA = 0.f, lB = 0.f;

  int4 xA0, xA1, xB0, xB1; float4 xT0, xT1;
  int4 yA0, yA1, yB0, yB1; float4 yT0, yT1;

  // prologue: 2 chunks of DMA in flight, chunk 0 regs, full drain once.
  DMA2(0);
  DMA2(1);
  FETCH(0, xA0, xA1, xB0, xB1, xT0, xT1);
  asm volatile("s_waitcnt vmcnt(0)" ::: "memory");
  __builtin_amdgcn_s_barrier();

  for (int c = 0; c < NCHUNK; c += 2) {
    // iter A: compute c (X), prefetch regs c+1 (Y), DMA c+2
    if (c + 2 < NCHUNK) DMA2(c + 2);
    FETCH(c + 1, yA0, yA1, yB0, yB1, yT0, yT1);
    COMPUTE(c, xA0, xA1, xB0, xB1, xT0, xT1);
    // >=4 VMEM ops newer than DMA(c+1) are in flight -> vmcnt(4) guarantees
    // DMA(c+1) landed without draining this iter's prefetches.
    asm volatile("s_waitcnt vmcnt(4)" ::: "memory");
    __builtin_amdgcn_s_barrier();

    // iter B: compute c+1 (Y), prefetch regs c+2 (X), DMA c+3
    if (c + 3 < NCHUNK) DMA2(c + 3);
    if (c + 2 < NCHUNK) FETCH(c + 2, xA0, xA1, xB0, xB1, xT0, xT1);
    COMPUTE(c + 1, yA0, yA1, yB0, yB1, yT0, yT1);
    if (c + 2 < NCHUNK) {
      asm volatile("s_waitcnt vmcnt(4)" ::: "memory");
      __builtin_amdgcn_s_barrier();
    }
  }

  // row-sum partials: lanes {m, m+16, m+32, m+48} hold same row
  lA += __shfl_xor(lA, 16); lA += __shfl_xor(lA, 32);
  lB += __shfl_xor(lB, 16); lB += __shfl_xor(lB, 32);
  if (quad == 0) {
    lpart[(size_t)cs * NN + rowA] = lA;
    lpart[(size_t)cs * NN + rowB] = lB;
  }

  // C/D layout: row = quad*4 + r, col = nb*16 + m. Plain stores to partial slice.
  float* po = part + ((size_t)cs * NN + row0 + wave * 32) * DIM;
#pragma unroll
  for (int nb = 0; nb < 8; nb++) {
#pragma unroll
    for (int r = 0; r < 4; r++) {
      po[(size_t)(quad * 4 + r) * DIM + nb * 16 + m] = accA[nb][r];
      po[(size_t)(16 + quad * 4 + r) * DIM + nb * 16 + m] = accB[nb][r];
    }
  }
}

// ---------------- kernel 3: reduce partials + denominators + relu ------------
__global__ __launch_bounds__(256) void k3_fin(const float* __restrict__ part,
                                              const float* __restrict__ lpart,
                                              float* __restrict__ out) {
  __shared__ float li[8];
  const int base = blockIdx.x * 256;       // float4 index base; block = 8 rows
  const int idx = base + (int)threadIdx.x;
  if (threadIdx.x < 8) {
    const int r = (base >> 5) + (int)threadIdx.x;
    float l = 0.f;
#pragma unroll
    for (int c2 = 0; c2 < CSPLIT; c2++) l += lpart[(size_t)c2 * NN + r];
    li[threadIdx.x] = 1.0f / l;
  }
  const float4* p4 = (const float4*)part;
  float4 acc = p4[idx];
#pragma unroll
  for (int c2 = 1; c2 < CSPLIT; c2++) {
    float4 v = p4[(size_t)c2 * (NN * DIM / 4) + idx];
    acc.x += v.x; acc.y += v.y; acc.z += v.z; acc.w += v.w;
  }
  __syncthreads();
  const float liv = li[threadIdx.x >> 5];
  float4 o;
  o.x = fmaxf(acc.x * liv, 0.f);
  o.y = fmaxf(acc.y * liv, 0.f);
  o.z = fmaxf(acc.z * liv, 0.f);
  o.w = fmaxf(acc.w * liv, 0.f);
  ((float4*)out)[idx] = o;
}

extern "C" void kernel_launch(void* const* d_in, const int* in_sizes, int n_in,
                              void* d_out, int out_size, void* d_ws, size_t ws_size,
                              hipStream_t stream) {
  (void)in_sizes; (void)n_in; (void)out_size; (void)ws_size;
  const float* emb = (const float*)d_in[0];
  const int* adj = (const int*)d_in[1];
  const float* W = (const float*)d_in[2];
  const float* a = (const float*)d_in[3];
  float* out = (float*)d_out;

  char* ws = (char*)d_ws;
  __bf16* Vt = (__bf16*)ws;                       // 3,145,728 B
  float* s = (float*)(ws + 3145728);              // 49,152 B (log2e-scaled)
  float* t = (float*)(ws + 3194880);              // 49,152 B (log2e-scaled)
  float* lpart = (float*)(ws + 3244032);          // 8*12288*4 = 393,216 B
  float* tmax = (float*)(ws + 3686400);           // 256 B
  float* part = (float*)(ws + 3686656);           // 8*12288*128*4 = 50,331,648 B

  k1_gemm<<<NN / 64, 256, 0, stream>>>(emb, W, a, Vt, s, t);
  ktmax<<<1, 256, 0, stream>>>(t, tmax);
  dim3 g2(NN / 128, CSPLIT);
  k2_attn<<<g2, 256, 0, stream>>>(adj, Vt, s, t, tmax, part, lpart);
  k3_fin<<<NN * DIM / 4 / 256, 256, 0, stream>>>(part, lpart, out);
}